// Round 4
// baseline (741.570 us; speedup 1.0000x reference)
//
#include <hip/hip_runtime.h>
#include <cmath>
#include <stdint.h>

#define B_ 32
#define T_ 2048
#define H_ 1024

typedef __attribute__((ext_vector_type(8))) __bf16 bf16x8;
typedef __attribute__((ext_vector_type(4))) float f32x4;

__device__ inline void async_copy16(const void* g, void* l) {
    __builtin_amdgcn_global_load_lds((const __attribute__((address_space(1))) uint32_t*)g,
                                     (__attribute__((address_space(3))) uint32_t*)l, 16, 0, 0);
}

__device__ inline float fast_tanh(float x) {
    float e = __expf(2.f * x);
    return 1.f - 2.f / (e + 1.f);
}

__global__ __launch_bounds__(256) void zero_kernel(float* __restrict__ p, int n) {
    int i = blockIdx.x * 256 + threadIdx.x;
    if (i < n) p[i] = 0.f;
}

// fp32 -> bf16, 8 elements per thread; n must be a multiple of 2048 per grid sizing
__global__ __launch_bounds__(256) void convert_kernel(const float* __restrict__ in,
                                                      __bf16* __restrict__ out) {
    size_t i = (size_t)(blockIdx.x * 256 + threadIdx.x) * 8;
    const float4* p = (const float4*)(in + i);
    float4 v0 = p[0], v1 = p[1];
    bf16x8 o;
    o[0] = (__bf16)v0.x; o[1] = (__bf16)v0.y; o[2] = (__bf16)v0.z; o[3] = (__bf16)v0.w;
    o[4] = (__bf16)v1.x; o[5] = (__bf16)v1.y; o[6] = (__bf16)v1.z; o[7] = (__bf16)v1.w;
    *(bf16x8*)(out + i) = o;
}

// kq[b,h] = sum_j Wq[h,j]*dec[b,j] + bq[h] + bk[h]
__global__ __launch_bounds__(256) void q_kernel(const float* __restrict__ dec,
                                                const float* __restrict__ Wq,
                                                const float* __restrict__ bq,
                                                const float* __restrict__ bk,
                                                float* __restrict__ kq) {
    int b = blockIdx.x;
    int hc = blockIdx.y;
    __shared__ float ds[H_];
    for (int i = threadIdx.x; i < H_; i += 256) ds[i] = dec[b * H_ + i];
    __syncthreads();
    int h = hc * 256 + threadIdx.x;
    const float4* w = (const float4*)(Wq + (size_t)h * H_);
    float acc = 0.f;
#pragma unroll 8
    for (int j = 0; j < H_ / 4; j++) {
        float4 v = w[j];
        acc += v.x * ds[4 * j] + v.y * ds[4 * j + 1] + v.z * ds[4 * j + 2] + v.w * ds[4 * j + 3];
    }
    kq[b * H_ + h] = acc + bq[h] + bk[h];
}

// MFMA score GEMM: score[b,t] += sum_h Wout[h]*tanh(enc[t,:]·Wk[h,:] + kq[b,h])
//
// Round-3: 8-phase fine interleave (m201 port). 256x256 tile, BK=64,
// 8 waves 2Mx4N, per-wave 128x64 = 2par x 4mfl x 4nf frags.
// LDS 128 KB: 2 buffers x (A 32KB + B 32KB), alternate per K-tile.
// 4 phases per K-tile, phase p=(ks,par): ks=p>>1, par=p&1:
//   { ds_read A-subtile (4) [+B ks-half (8) at p=0,2];
//     stage quarter p of K-tile kt+1 (2 x global_load_lds);
//     s_barrier; setprio(1); 16 MFMA (acc[par][m][nf] += A x B); setprio(0);
//     [vmcnt(4) at p=1,3]; s_barrier }
// Chunk layouts (chunk = 16B = 8 bf16):
//   A: c = ks*1024 + par*512 + rh*256 + kq*64 + rin  (row = rh*128+par*64+rin, k = ks*32+kq*8)
//   B: c = ks*1024 + kq*256 + col                    (col 0..255, k = ks*32+kq*8)
// Stage instr p covers chunks [p*512, p*512+512) = exactly the quarter read at
// phase p of the NEXT K-tile -> every load has >=3 phases of latency cover, and
// in-order vmcnt(4) (2 stage-instrs/phase, 8/K-tile) guarantees prefix landing.
// Reads are 16-lane-contiguous 256B -> conflict-free; staging dest is linear
// (wave-uniform base + lane*16) as global_load_lds requires.
__global__ __launch_bounds__(512, 2) void score_mfma(const __bf16* __restrict__ encb,
                                                     const __bf16* __restrict__ Wkb,
                                                     const float* __restrict__ kq,
                                                     const float* __restrict__ Wout,
                                                     float* __restrict__ score) {
    __shared__ __align__(16) __bf16 lds[2 * 32768];  // 128 KB

    // XCD-aware bijective remap: gridDim=(4,256), lin%8 = XCD. XCD x owns
    // m-blocks [x*32, x*32+32) x all 4 n-blocks -> encb panel L2-resident.
    const int lin = blockIdx.x + 4 * blockIdx.y;
    const int xcd = lin & 7;
    const int idx = lin >> 3;              // 0..127
    const int mblk = xcd * 32 + (idx >> 2);
    const int nblk = idx & 3;
    const int m0 = mblk * 256;
    const int h0 = nblk * 256;
    const int b = m0 >> 11;                // 2048 tokens per b; 256 | 2048

    const int tid = threadIdx.x;
    const int lane = tid & 63;
    const int w = tid >> 6;                // 0..7
    const int wm = w >> 2;                 // 0..1  (128-row half)
    const int wn = w & 3;                  // 0..3  (64-col slice)
    const int q4 = lane >> 4, l15 = lane & 15;

    // staging source pointers (per-lane); instr p adds the quarter offsets
    const __bf16* gA = encb + (size_t)(m0 + (tid >> 8) * 128 + (tid & 63)) * H_ +
                       ((tid >> 6) & 3) * 8;
    const __bf16* gB = Wkb + (size_t)(h0 + (tid & 255)) * H_ + (tid >> 8) * 8;

    f32x4 acc[2][4][4];  // [par][mfl][nf]
#pragma unroll
    for (int p = 0; p < 2; p++)
#pragma unroll
        for (int i = 0; i < 4; i++)
#pragma unroll
            for (int j = 0; j < 4; j++) acc[p][i][j] = (f32x4){0.f, 0.f, 0.f, 0.f};

    // stage quarter p of K-tile kt1 into buffer kt1&1
#define STG(p, kt1)                                                         \
    do {                                                                    \
        __bf16* Ln = lds + (((kt1) & 1) ? 32768 : 0);                       \
        async_copy16(gA + (size_t)((p) & 1) * 64 * H_ + ((p) >> 1) * 32 +   \
                         (kt1) * 64,                                        \
                     Ln + (p) * 4096 + w * 512);                            \
        async_copy16(gB + ((p) & 1) * 16 + ((p) >> 1) * 32 + (kt1) * 64,    \
                     Ln + 16384 + (p) * 4096 + w * 512);                    \
    } while (0)

#define PHASE(KS, PAR, BFR, LOADB)                                              \
    do {                                                                        \
        if (LOADB) {                                                            \
            _Pragma("unroll")                                                   \
            for (int nf = 0; nf < 4; nf++)                                      \
                BFR[nf] = *(const bf16x8*)(L + 16384 +                          \
                    (size_t)((KS) * 1024 + q4 * 256 + wn * 64 + nf * 16 + l15) * 8); \
        }                                                                       \
        bf16x8 afr[4];                                                          \
        _Pragma("unroll")                                                       \
        for (int m = 0; m < 4; m++)                                             \
            afr[m] = *(const bf16x8*)(L +                                       \
                (size_t)((KS) * 1024 + (PAR) * 512 + wm * 256 + q4 * 64 + m * 16 + l15) * 8); \
        if (st) STG((KS) * 2 + (PAR), kt + 1);                                  \
        __builtin_amdgcn_s_barrier();                                           \
        __builtin_amdgcn_sched_barrier(0);                                      \
        __builtin_amdgcn_s_setprio(1);                                          \
        _Pragma("unroll")                                                       \
        for (int m = 0; m < 4; m++)                                             \
            _Pragma("unroll")                                                   \
            for (int nf = 0; nf < 4; nf++)                                      \
                acc[PAR][m][nf] = __builtin_amdgcn_mfma_f32_16x16x32_bf16(      \
                    afr[m], BFR[nf], acc[PAR][m][nf], 0, 0, 0);                 \
        __builtin_amdgcn_s_setprio(0);                                          \
    } while (0)

    // prologue: stage all 4 quarters of K-tile 0 (issue order = quarters 0..3)
    {
        const int kt = -1;  // unused by STG
        (void)kt;
        STG(0, 0); STG(1, 0); STG(2, 0); STG(3, 0);
    }
    asm volatile("s_waitcnt vmcnt(4)" ::: "memory");
    __builtin_amdgcn_s_barrier();
    __builtin_amdgcn_sched_barrier(0);

    for (int kt = 0; kt < 16; ++kt) {
        const __bf16* L = lds + ((kt & 1) ? 32768 : 0);
        const bool st = kt < 15;
        bf16x8 bfr0[4], bfr1[4];

        PHASE(0, 0, bfr0, true);            // phase 0: ks0, rows par0
        __builtin_amdgcn_s_barrier();
        __builtin_amdgcn_sched_barrier(0);

        PHASE(0, 1, bfr0, false);           // phase 1: ks0, rows par1
        if (st) asm volatile("s_waitcnt vmcnt(4)" ::: "memory");
        else    asm volatile("s_waitcnt vmcnt(0)" ::: "memory");
        __builtin_amdgcn_s_barrier();
        __builtin_amdgcn_sched_barrier(0);

        PHASE(1, 0, bfr1, true);            // phase 2: ks1, rows par0
        __builtin_amdgcn_s_barrier();
        __builtin_amdgcn_sched_barrier(0);

        PHASE(1, 1, bfr1, false);           // phase 3: ks1, rows par1
        asm volatile("s_waitcnt vmcnt(4)" ::: "memory");
        __builtin_amdgcn_s_barrier();
        __builtin_amdgcn_sched_barrier(0);
    }
#undef PHASE
#undef STG

    // epilogue: per row, sum_h wout[h]*tanh(K + kq) over this wave's 64 columns
    float wv[4], kqv[4];
#pragma unroll
    for (int nf = 0; nf < 4; nf++) {
        int h = h0 + wn * 64 + nf * 16 + l15;
        wv[nf] = Wout[h];
        kqv[nf] = kq[b * H_ + h];
    }
#pragma unroll
    for (int par = 0; par < 2; par++) {
#pragma unroll
        for (int mf = 0; mf < 4; mf++) {
#pragma unroll
            for (int r = 0; r < 4; r++) {
                float s = 0.f;
#pragma unroll
                for (int nf = 0; nf < 4; nf++)
                    s += wv[nf] * fast_tanh(acc[par][mf][nf][r] + kqv[nf]);
#pragma unroll
                for (int m = 1; m < 16; m <<= 1) s += __shfl_xor(s, m, 64);
                if (l15 == 0)
                    atomicAdd(&score[m0 + wm * 128 + par * 64 + mf * 16 + q4 * 4 + r], s);
            }
        }
    }
}

// ---------- fp32 fallback score path (used only if ws too small) ----------
#define BK 32
#define ASTR 68
#define BSTR 132
__global__ __launch_bounds__(256) void score_fp32(const float* __restrict__ enc,
                                                  const float* __restrict__ Wk,
                                                  const float* __restrict__ kq,
                                                  const float* __restrict__ Wout,
                                                  float* __restrict__ score) {
    __shared__ __align__(16) float As[BK * ASTR];
    __shared__ __align__(16) float Bs[BK * BSTR];
    __shared__ float wout_s[128];
    __shared__ float kq_s[128];
    const int m0 = blockIdx.x * 64;
    const int h0 = blockIdx.y * 128;
    const int b = m0 >> 11;
    const int tid = threadIdx.x;
    const int tx = tid & 15;
    const int ty = tid >> 4;
    if (tid < 128) {
        wout_s[tid] = Wout[h0 + tid];
        kq_s[tid] = kq[b * H_ + h0 + tid];
    }
    float acc[4][8];
#pragma unroll
    for (int i = 0; i < 4; i++)
#pragma unroll
        for (int j = 0; j < 8; j++) acc[i][j] = 0.f;
    for (int k0 = 0; k0 < H_; k0 += BK) {
        __syncthreads();
#pragma unroll
        for (int r = 0; r < 2; r++) {
            int li = tid + r * 256;
            int tok = li >> 3, kg = li & 7;
            float4 v = *(const float4*)(enc + (size_t)(m0 + tok) * H_ + k0 + kg * 4);
            As[(kg * 4 + 0) * ASTR + tok] = v.x;
            As[(kg * 4 + 1) * ASTR + tok] = v.y;
            As[(kg * 4 + 2) * ASTR + tok] = v.z;
            As[(kg * 4 + 3) * ASTR + tok] = v.w;
        }
#pragma unroll
        for (int r = 0; r < 4; r++) {
            int li = tid + r * 256;
            int h = li >> 3, kg = li & 7;
            float4 v = *(const float4*)(Wk + (size_t)(h0 + h) * H_ + k0 + kg * 4);
            Bs[(kg * 4 + 0) * BSTR + h] = v.x;
            Bs[(kg * 4 + 1) * BSTR + h] = v.y;
            Bs[(kg * 4 + 2) * BSTR + h] = v.z;
            Bs[(kg * 4 + 3) * BSTR + h] = v.w;
        }
        __syncthreads();
#pragma unroll
        for (int kk = 0; kk < BK; kk++) {
            float4 a4 = *(const float4*)&As[kk * ASTR + ty * 4];
            float4 b4a = *(const float4*)&Bs[kk * BSTR + tx * 4];
            float4 b4b = *(const float4*)&Bs[kk * BSTR + 64 + tx * 4];
            float av[4] = {a4.x, a4.y, a4.z, a4.w};
            float bv[8] = {b4a.x, b4a.y, b4a.z, b4a.w, b4b.x, b4b.y, b4b.z, b4b.w};
#pragma unroll
            for (int i = 0; i < 4; i++)
#pragma unroll
                for (int j = 0; j < 8; j++) acc[i][j] += av[i] * bv[j];
        }
    }
    float wv[8], kqv[8];
#pragma unroll
    for (int j = 0; j < 8; j++) {
        int hl = (j < 4) ? (tx * 4 + j) : (64 + tx * 4 + (j - 4));
        wv[j] = wout_s[hl];
        kqv[j] = kq_s[hl];
    }
#pragma unroll
    for (int i = 0; i < 4; i++) {
        float s = 0.f;
#pragma unroll
        for (int j = 0; j < 8; j++) s += wv[j] * tanhf(acc[i][j] + kqv[j]);
#pragma unroll
        for (int m = 1; m < 16; m <<= 1) s += __shfl_xor(s, m, 64);
        if (tx == 0) atomicAdd(&score[m0 + ty * 4 + i], s);
    }
}
// --------------------------------------------------------------------------

__global__ __launch_bounds__(256) void softmax_kernel(float* __restrict__ score) {
    int b = blockIdx.x, tid = threadIdx.x;
    float* s = score + b * T_;
    __shared__ float red[8];
    float v[8];
    float mx = -1e30f;
#pragma unroll
    for (int i = 0; i < 8; i++) {
        v[i] = s[tid + i * 256];
        mx = fmaxf(mx, v[i]);
    }
#pragma unroll
    for (int m = 32; m >= 1; m >>= 1) mx = fmaxf(mx, __shfl_xor(mx, m, 64));
    if ((tid & 63) == 0) red[tid >> 6] = mx;
    __syncthreads();
    mx = fmaxf(fmaxf(red[0], red[1]), fmaxf(red[2], red[3]));
    float sum = 0.f;
#pragma unroll
    for (int i = 0; i < 8; i++) {
        v[i] = __expf(v[i] - mx);
        sum += v[i];
    }
#pragma unroll
    for (int m = 32; m >= 1; m >>= 1) sum += __shfl_xor(sum, m, 64);
    if ((tid & 63) == 0) red[4 + (tid >> 6)] = sum;
    __syncthreads();
    sum = red[4] + red[5] + red[6] + red[7];
    float inv = 1.f / sum;
#pragma unroll
    for (int i = 0; i < 8; i++) s[tid + i * 256] = v[i] * inv;
}

// context[b,h] = sum_t attn[b,t]*enc[b,t,h]; fp32 enc for accuracy. grid (32 tsplit, B)
__global__ __launch_bounds__(256) void context_kernel(const float* __restrict__ enc,
                                                      const float* __restrict__ attn,
                                                      float* __restrict__ out) {
    int ts = blockIdx.x, b = blockIdx.y;
    const float* e = enc + (size_t)b * T_ * H_ + (size_t)ts * 64 * H_ + threadIdx.x * 4;
    const float* a = attn + b * T_ + ts * 64;
    float4 acc = {0.f, 0.f, 0.f, 0.f};
#pragma unroll 4
    for (int t = 0; t < 64; t++) {
        float av = a[t];
        float4 v = *(const float4*)(e + (size_t)t * H_);
        acc.x += av * v.x; acc.y += av * v.y; acc.z += av * v.z; acc.w += av * v.w;
    }
    float* o = out + b * H_ + threadIdx.x * 4;
    atomicAdd(o + 0, acc.x);
    atomicAdd(o + 1, acc.y);
    atomicAdd(o + 2, acc.z);
    atomicAdd(o + 3, acc.w);
}

extern "C" void kernel_launch(void* const* d_in, const int* in_sizes, int n_in,
                              void* d_out, int out_size, void* d_ws, size_t ws_size,
                              hipStream_t stream) {
    const float* enc = (const float*)d_in[0];
    const float* dec = (const float*)d_in[1];
    const float* Wk = (const float*)d_in[2];
    const float* bk = (const float*)d_in[3];
    const float* Wq = (const float*)d_in[4];
    const float* bq = (const float*)d_in[5];
    const float* Wout = (const float*)d_in[6];
    // d_in[7] = bout: cancels under softmax. d_in[8] = inputs: unused.
    float* out = (float*)d_out;

    const size_t encb_bytes = (size_t)B_ * T_ * H_ * 2;   // 134217728
    const size_t wkb_bytes = (size_t)H_ * H_ * 2;         // 2097152
    const size_t need = encb_bytes + wkb_bytes + (size_t)B_ * H_ * 4 + (size_t)B_ * T_ * 4;

    if (ws_size >= need) {
        __bf16* encb = (__bf16*)d_ws;
        __bf16* Wkb = (__bf16*)((char*)d_ws + encb_bytes);
        float* kq = (float*)((char*)d_ws + encb_bytes + wkb_bytes);
        float* score = kq + B_ * H_;

        convert_kernel<<<(B_ * T_ * H_) / 2048, 256, 0, stream>>>(enc, encb);
        convert_kernel<<<(H_ * H_) / 2048, 256, 0, stream>>>(Wk, Wkb);
        q_kernel<<<dim3(B_, 4), 256, 0, stream>>>(dec, Wq, bq, bk, kq);
        zero_kernel<<<(B_ * T_ + 255) / 256, 256, 0, stream>>>(score, B_ * T_);
        zero_kernel<<<(B_ * H_ + 255) / 256, 256, 0, stream>>>(out, B_ * H_);
        score_mfma<<<dim3(4, 256), 512, 0, stream>>>(encb, Wkb, kq, Wout, score);
        softmax_kernel<<<B_, 256, 0, stream>>>(score);
        context_kernel<<<dim3(32, B_), 256, 0, stream>>>(enc, score, out);
    } else {
        float* kq = (float*)d_ws;
        float* score = kq + B_ * H_;
        q_kernel<<<dim3(B_, 4), 256, 0, stream>>>(dec, Wq, bq, bk, kq);
        zero_kernel<<<(B_ * T_ + 255) / 256, 256, 0, stream>>>(score, B_ * T_);
        zero_kernel<<<(B_ * H_ + 255) / 256, 256, 0, stream>>>(out, B_ * H_);
        score_fp32<<<dim3(1024, 8), 256, 0, stream>>>(enc, Wk, kq, Wout, score);
        softmax_kernel<<<B_, 256, 0, stream>>>(score);
        context_kernel<<<dim3(32, B_), 256, 0, stream>>>(enc, score, out);
    }
}